// Round 8
// baseline (462.095 us; speedup 1.0000x reference)
//
#include <hip/hip_runtime.h>

// ---------------------------------------------------------------------------
// BipartiteLayer: xp = x@W_in+b ; s = exp(-|[xp_i[s],xp_m[e]]@W_score+b|) ;
// scatter mean/max of xp_pair*s ; h = relu([x,xp,mean,max]@W_out+b)
//
// Pipeline:
//   k_prep_wt   : W (f32, KxN) -> Wt (N rows x K, bf16) transpose
//   k_gemm_in   : MFMA bf16 K=128 one-shot; fused bias, xp store, a=xp.Ws
//   k_edge      : per-edge score + linked-list CSR build (atomicExch)
//   k_agg_gemm  : FUSED per 16 nodes: wave-per-node gather-reduce -> H rows
//                 in LDS (swizzled), then 16x128 MFMA GEMM K=1408 vs Wt(L2),
//                 bias+relu -> out. Kills the 2x141MB H HBM round-trip.
// ---------------------------------------------------------------------------

typedef __attribute__((ext_vector_type(8))) short bf16x8;   // 8 bf16 = 4 VGPR
typedef __attribute__((ext_vector_type(4))) float f32x4;

static __device__ __forceinline__ unsigned short f2bf(float f) {
  unsigned int u = __float_as_uint(f);
  u = (u + 0x7FFFu + ((u >> 16) & 1u)) >> 16;   // RNE
  return (unsigned short)u;
}
static __device__ __forceinline__ float bf2f(unsigned short s) {
  return __uint_as_float(((unsigned int)s) << 16);
}

#define GLD16(gp, lp)                                                        \
  __builtin_amdgcn_global_load_lds(                                          \
      (const __attribute__((address_space(1))) void*)(gp),                   \
      (__attribute__((address_space(3))) void*)(lp), 16, 0, 0)

// ---- transpose W (KxNcol f32) -> Wt[col][k] bf16 ---------------------------
__global__ void k_prep_wt(const float* __restrict__ Wo,
                          unsigned short* __restrict__ Wt, int K, int Ncol) {
  int idx = blockIdx.x * blockDim.x + threadIdx.x;
  if (idx >= K * Ncol) return;
  int k = idx / Ncol, c = idx % Ncol;
  Wt[(size_t)c * K + k] = f2bf(Wo[idx]);
}

// ---- input GEMM (MFMA): [N,128]f32 @ [128,256] -> xp bf16, a=xp.Ws --------
__global__ __launch_bounds__(256) void k_gemm_in(
    const float* __restrict__ x, const unsigned short* __restrict__ Wint,
    const float* __restrict__ bias, const float* __restrict__ Wsc,
    unsigned short* __restrict__ xp, float* __restrict__ a_out, int N) {
  __shared__ __align__(16) unsigned short Ab[64 * 16 * 8];    // 16 KB
  __shared__ __align__(16) unsigned short Bb[256 * 16 * 8];   // 64 KB
  const int tid = threadIdx.x;
  const int l = tid & 63;
  const int lr = l & 15, lg = l >> 4;
  const int w = tid >> 6, wr = w >> 1, wc = w & 1;
  const int r0 = blockIdx.x * 64;
  const int wbase = tid & 192;                  // w*64, wave-uniform

  // B: 256 rows x 16 chunks (16B each) = 64 KB -> 16 iterations of 256 lanes
#pragma unroll
  for (int i = 0; i < 16; ++i) {
    int g = i * 256 + tid;
    int row = g >> 4, c = g & 15;
    int sc = c ^ (row & 7);
    GLD16(Wint + (size_t)row * 128 + sc * 8,
          &Bb[(size_t)(i * 256 + wbase) * 8]);
  }
  // A: 64 rows x 16 chunks, reg-stage f32->bf16, swizzled per-lane ds_write
#pragma unroll
  for (int i = 0; i < 4; ++i) {
    int g = i * 256 + tid;
    int row = g >> 4, c = g & 15;
    int ar = min(r0 + row, N - 1);
    const float* src = x + (size_t)ar * 128 + c * 8;
    float4 u = *(const float4*)src;
    float4 v = *(const float4*)(src + 4);
    bf16x8 h;
    h[0] = (short)f2bf(u.x); h[1] = (short)f2bf(u.y);
    h[2] = (short)f2bf(u.z); h[3] = (short)f2bf(u.w);
    h[4] = (short)f2bf(v.x); h[5] = (short)f2bf(v.y);
    h[6] = (short)f2bf(v.z); h[7] = (short)f2bf(v.w);
    *(bf16x8*)&Ab[(size_t)(row * 16 + (c ^ (row & 7))) * 8] = h;
  }
  __syncthreads();

  f32x4 acc[2][8];
#pragma unroll
  for (int m = 0; m < 2; ++m)
#pragma unroll
    for (int t = 0; t < 8; ++t) {
      f32x4 z = {0.f, 0.f, 0.f, 0.f};
      acc[m][t] = z;
    }
#pragma unroll
  for (int kk = 0; kk < 4; ++kk) {
    int chq = kk * 4 + lg;
    bf16x8 a[2], bt[8];
#pragma unroll
    for (int m = 0; m < 2; ++m) {
      int row = wr * 32 + m * 16 + lr;
      a[m] = *(const bf16x8*)&Ab[(row * 16 + (chq ^ (row & 7))) * 8];
    }
#pragma unroll
    for (int t = 0; t < 8; ++t) {
      int row = wc * 128 + t * 16 + lr;
      bt[t] = *(const bf16x8*)&Bb[(row * 16 + (chq ^ (row & 7))) * 8];
    }
#pragma unroll
    for (int m = 0; m < 2; ++m)
#pragma unroll
      for (int t = 0; t < 8; ++t)
        acc[m][t] = __builtin_amdgcn_mfma_f32_16x16x32_bf16(
            a[m], bt[t], acc[m][t], 0, 0, 0);
  }

  // epilogue: bias, xp store (bf16), fused a = (xp+bias) . Wsc
  float wscv[8], bb[8];
#pragma unroll
  for (int t = 0; t < 8; ++t) {
    int c = wc * 128 + t * 16 + lr;
    wscv[t] = Wsc[c];
    bb[t] = bias[c];
  }
#pragma unroll
  for (int m = 0; m < 2; ++m) {
    int rb = r0 + wr * 32 + m * 16 + lg * 4;    // C/D: col=lane&15, row=lg*4+reg
    float p0 = 0.f, p1 = 0.f, p2 = 0.f, p3 = 0.f;
#pragma unroll
    for (int t = 0; t < 8; ++t) {
      int c = wc * 128 + t * 16 + lr;
      float v0 = acc[m][t][0] + bb[t];
      float v1 = acc[m][t][1] + bb[t];
      float v2 = acc[m][t][2] + bb[t];
      float v3 = acc[m][t][3] + bb[t];
      if (rb + 0 < N) xp[(size_t)(rb + 0) * 256 + c] = f2bf(v0);
      if (rb + 1 < N) xp[(size_t)(rb + 1) * 256 + c] = f2bf(v1);
      if (rb + 2 < N) xp[(size_t)(rb + 2) * 256 + c] = f2bf(v2);
      if (rb + 3 < N) xp[(size_t)(rb + 3) * 256 + c] = f2bf(v3);
      p0 = fmaf(v0, wscv[t], p0); p1 = fmaf(v1, wscv[t], p1);
      p2 = fmaf(v2, wscv[t], p2); p3 = fmaf(v3, wscv[t], p3);
    }
#pragma unroll
    for (int off = 1; off < 16; off <<= 1) {    // butterfly within 16-lane grp
      p0 += __shfl_xor(p0, off); p1 += __shfl_xor(p1, off);
      p2 += __shfl_xor(p2, off); p3 += __shfl_xor(p3, off);
    }
    if (lr == 0) {
      if (rb + 0 < N) atomicAdd(a_out + rb + 0, p0);
      if (rb + 1 < N) atomicAdd(a_out + rb + 1, p1);
      if (rb + 2 < N) atomicAdd(a_out + rb + 2, p2);
      if (rb + 3 < N) atomicAdd(a_out + rb + 3, p3);
    }
  }
}

// ---- per-edge score + linked-list CSR -------------------------------------
__global__ void k_edge(const int* __restrict__ es, const int* __restrict__ ee,
                       int E, const float* __restrict__ a_i,
                       const float* __restrict__ a_m,
                       const float* __restrict__ bsc,
                       float* __restrict__ slist, int* __restrict__ head_i,
                       int* __restrict__ next_i, int* __restrict__ head_m,
                       int* __restrict__ next_m) {
  int e = blockIdx.x * blockDim.x + threadIdx.x;
  if (e >= E) return;
  int s = es[e], m = ee[e];
  float t = a_i[s] + a_m[m] + bsc[0];
  slist[e] = expf(-fabsf(t));
  next_i[e] = atomicExch(head_i + s, e);
  next_m[e] = atomicExch(head_m + m, e);
}

// ---- FUSED agg + output GEMM ----------------------------------------------
// Block: 512 thr / 8 waves; 16 nodes per block.
// Phase 1: wave-per-node gather-reduce -> H row (1408 bf16) in LDS, swizzled
//          chunk ^= row&7 (same family as R5/R7 gemm_out: 0 bank conflicts).
// Phase 2: 16x128 MFMA GEMM K=1408; A from LDS, B = Wt rows from global(L2);
//          wave w owns output cols [16w,16w+16); bias+relu -> out f32.
// H = [x(128) | xp(256) | mean(512) | max(512)]
__global__ __launch_bounds__(512) void k_agg_gemm(
    const float* __restrict__ x_own, const unsigned short* __restrict__ xp_own,
    const unsigned short* __restrict__ xp_oth, const int* __restrict__ head,
    const int* __restrict__ nxt, const int* __restrict__ oth_id,
    const float* __restrict__ slist, const unsigned short* __restrict__ Wt,
    const float* __restrict__ bias, float* __restrict__ out,
    int N, int own_off, int oth_off) {
  __shared__ __align__(16) unsigned short Hs[16 * 1408];   // 44 KB
  const int tid = threadIdx.x;
  const int l = tid & 63;
  const int wv = tid >> 6;                      // 0..7
  const int base = blockIdx.x * 16;

  auto st4 = [&](int row, int col, ushort4 v) {
    int ch = col >> 3, wi = col & 7;
    *(ushort4*)&Hs[(size_t)row * 1408 + ((ch ^ (row & 7)) << 3) + wi] = v;
  };
  auto st2 = [&](int row, int col, ushort2 v) {
    int ch = col >> 3, wi = col & 7;
    *(ushort2*)&Hs[(size_t)row * 1408 + ((ch ^ (row & 7)) << 3) + wi] = v;
  };

  // ---- phase 1: build 16 H rows (2 nodes per wave) ----
  for (int rr = wv; rr < 16; rr += 8) {
    int node = base + rr;
    if (node >= N) node = N - 1;                // duplicate row; store-guarded
    ushort4 xo = *(const ushort4*)(xp_own + (size_t)node * 256 + 4 * l);
    float xp0 = bf2f(xo.x), xp1 = bf2f(xo.y), xp2 = bf2f(xo.z), xp3 = bf2f(xo.w);
    float2 xv = *(const float2*)(x_own + (size_t)node * 128 + 2 * l);
    st2(rr, 2 * l, make_ushort2(f2bf(xv.x), f2bf(xv.y)));
    st4(rr, 128 + 4 * l, xo);

    float sum_s = 0.f, mx_s = -1e30f, mn_s = 1e30f;
    float sv0 = 0.f, sv1 = 0.f, sv2 = 0.f, sv3 = 0.f;
    float mv0 = -1e30f, mv1 = -1e30f, mv2 = -1e30f, mv3 = -1e30f;
    int dg = 0;
    for (int e = head[node]; e >= 0; e = nxt[e]) {   // uniform chain walk
      int o = oth_id[e];
      float s = slist[e];
      ushort4 ov = *(const ushort4*)(xp_oth + (size_t)o * 256 + 4 * l);
      float f0 = bf2f(ov.x), f1 = bf2f(ov.y), f2 = bf2f(ov.z), f3 = bf2f(ov.w);
      sv0 = fmaf(s, f0, sv0); sv1 = fmaf(s, f1, sv1);
      sv2 = fmaf(s, f2, sv2); sv3 = fmaf(s, f3, sv3);
      mv0 = fmaxf(mv0, s * f0); mv1 = fmaxf(mv1, s * f1);
      mv2 = fmaxf(mv2, s * f2); mv3 = fmaxf(mv3, s * f3);
      sum_s += s; mx_s = fmaxf(mx_s, s); mn_s = fminf(mn_s, s);
      ++dg;
    }
    float inv = 1.f / (float)(dg > 0 ? dg : 1);
    float ss = sum_s * inv;
    st4(rr, 384 + own_off + 4 * l, make_ushort4(
        f2bf(xp0 * ss), f2bf(xp1 * ss), f2bf(xp2 * ss), f2bf(xp3 * ss)));
    st4(rr, 384 + oth_off + 4 * l, make_ushort4(
        f2bf(sv0 * inv), f2bf(sv1 * inv), f2bf(sv2 * inv), f2bf(sv3 * inv)));
    float a0, a1, a2, a3;
    if (dg > 0) {
      a0 = fmaxf(fmaxf(xp0 * mx_s, xp0 * mn_s), 0.f);
      a1 = fmaxf(fmaxf(xp1 * mx_s, xp1 * mn_s), 0.f);
      a2 = fmaxf(fmaxf(xp2 * mx_s, xp2 * mn_s), 0.f);
      a3 = fmaxf(fmaxf(xp3 * mx_s, xp3 * mn_s), 0.f);
    } else {
      a0 = a1 = a2 = a3 = 0.f;
    }
    st4(rr, 896 + own_off + 4 * l, make_ushort4(f2bf(a0), f2bf(a1),
                                                f2bf(a2), f2bf(a3)));
    st4(rr, 896 + oth_off + 4 * l, make_ushort4(
        f2bf(fmaxf(mv0, 0.f)), f2bf(fmaxf(mv1, 0.f)),
        f2bf(fmaxf(mv2, 0.f)), f2bf(fmaxf(mv3, 0.f))));
  }
  __syncthreads();

  // ---- phase 2: out[16 rows][128 cols] = H @ Wt^T + b, relu ----
  const int lr = l & 15, lg = l >> 4;
  const int c = wv * 16 + lr;
  const unsigned short* Wr = Wt + (size_t)c * 1408;
  f32x4 acc = {0.f, 0.f, 0.f, 0.f};
#pragma unroll 4
  for (int kc = 0; kc < 44; ++kc) {
    bf16x8 a = *(const bf16x8*)&Hs[(size_t)lr * 1408 +
                                   (((kc * 4 + lg) ^ (lr & 7)) << 3)];
    bf16x8 b = *(const bf16x8*)(Wr + kc * 32 + lg * 8);
    acc = __builtin_amdgcn_mfma_f32_16x16x32_bf16(a, b, acc, 0, 0, 0);
  }
  float bb = bias[c];
#pragma unroll
  for (int j = 0; j < 4; ++j) {                 // C/D: col=lane&15, row=lg*4+j
    int row = base + lg * 4 + j;
    if (row < N) out[(size_t)row * 128 + c] = fmaxf(acc[j] + bb, 0.f);
  }
}

extern "C" void kernel_launch(void* const* d_in, const int* in_sizes, int n_in,
                              void* d_out, int out_size, void* d_ws,
                              size_t ws_size, hipStream_t stream) {
  const float* x_i  = (const float*)d_in[0];
  const float* x_m  = (const float*)d_in[1];
  const int*   ei   = (const int*)d_in[2];
  const float* Wi_i = (const float*)d_in[3];
  const float* bi_i = (const float*)d_in[4];
  const float* Wi_m = (const float*)d_in[5];
  const float* bi_m = (const float*)d_in[6];
  const float* Wsc  = (const float*)d_in[7];
  const float* bsc  = (const float*)d_in[8];
  const float* Wo_i = (const float*)d_in[9];
  const float* bo_i = (const float*)d_in[10];
  const float* Wo_m = (const float*)d_in[11];
  const float* bo_m = (const float*)d_in[12];
  float* out = (float*)d_out;

  int Ni = in_sizes[0] / 128, Nm = in_sizes[1] / 128, E = in_sizes[2] / 2;
  const int* es = ei;
  const int* ee = ei + E;

  char* p = (char*)d_ws;
  auto alloc = [&](size_t bytes) {
    char* q = p;
    p += (bytes + 255) & ~(size_t)255;
    return q;
  };
  unsigned short* xp_i = (unsigned short*)alloc((size_t)Ni * 256 * 2);
  unsigned short* xp_m = (unsigned short*)alloc((size_t)Nm * 256 * 2);
  float* a_i   = (float*)alloc((size_t)Ni * 4);
  float* a_m   = (float*)alloc((size_t)Nm * 4);
  float* slist = (float*)alloc((size_t)E * 4);
  int* head_i  = (int*)alloc((size_t)Ni * 4);
  int* head_m  = (int*)alloc((size_t)Nm * 4);
  int* next_i  = (int*)alloc((size_t)E * 4);
  int* next_m  = (int*)alloc((size_t)E * 4);
  unsigned short* Wt_i = (unsigned short*)alloc((size_t)128 * 1408 * 2);
  unsigned short* Wt_m = (unsigned short*)alloc((size_t)128 * 1408 * 2);
  unsigned short* Wint_i = (unsigned short*)alloc((size_t)256 * 128 * 2);
  unsigned short* Wint_m = (unsigned short*)alloc((size_t)256 * 128 * 2);
  if ((size_t)(p - (char*)d_ws) > ws_size) return;   // fixed scratch ~57 MB

  hipMemsetAsync(head_i, 0xFF, (size_t)Ni * 4, stream);
  hipMemsetAsync(head_m, 0xFF, (size_t)Nm * 4, stream);
  hipMemsetAsync(a_i, 0, (size_t)Ni * 4, stream);
  hipMemsetAsync(a_m, 0, (size_t)Nm * 4, stream);

  k_prep_wt<<<(1408 * 128 + 255) / 256, 256, 0, stream>>>(Wo_i, Wt_i, 1408, 128);
  k_prep_wt<<<(1408 * 128 + 255) / 256, 256, 0, stream>>>(Wo_m, Wt_m, 1408, 128);
  k_prep_wt<<<(128 * 256 + 255) / 256, 256, 0, stream>>>(Wi_i, Wint_i, 128, 256);
  k_prep_wt<<<(128 * 256 + 255) / 256, 256, 0, stream>>>(Wi_m, Wint_m, 128, 256);

  k_gemm_in<<<(Ni + 63) / 64, 256, 0, stream>>>(x_i, Wint_i, bi_i, Wsc, xp_i, a_i, Ni);
  k_gemm_in<<<(Nm + 63) / 64, 256, 0, stream>>>(x_m, Wint_m, bi_m, Wsc + 256, xp_m, a_m, Nm);

  k_edge<<<(E + 255) / 256, 256, 0, stream>>>(es, ee, E, a_i, a_m, bsc, slist,
                                              head_i, next_i, head_m, next_m);

  // intt side: own half of pooled cols at [0,256), gathered (mvtx) at [256,512)
  k_agg_gemm<<<(Ni + 15) / 16, 512, 0, stream>>>(
      x_i, xp_i, xp_m, head_i, next_i, ee, slist, Wt_i, bo_i,
      out, Ni, 0, 256);
  // mvtx side: gathered (intt) at [0,256), own half at [256,512)
  k_agg_gemm<<<(Nm + 15) / 16, 512, 0, stream>>>(
      x_m, xp_m, xp_i, head_m, next_m, es, slist, Wt_m, bo_m,
      out + (size_t)Ni * 128, Nm, 256, 0);
}